// Round 1
// baseline (349.356 us; speedup 1.0000x reference)
//
#include <hip/hip_runtime.h>

#define N_ROWS 4000000
#define MAX_TRI 6

__global__ __launch_bounds__(256) void rinter_area_kernel(
    const float* __restrict__ int_pts,
    const int* __restrict__ num_of_inter,
    float* __restrict__ out,
    int n)
{
    int i = blockIdx.x * blockDim.x + threadIdx.x;
    if (i >= n) return;

    // Load 16 floats = 4 x float4, fully coalesced in aggregate (all bytes used).
    const float4* p = (const float4*)(int_pts + (size_t)i * 16);
    float4 v0 = p[0];  // pts[0].x, pts[0].y, pts[1].x, pts[1].y
    float4 v1 = p[1];  // pts[2].x, pts[2].y, pts[3].x, pts[3].y
    float4 v2 = p[2];  // pts[4].x, pts[4].y, pts[5].x, pts[5].y
    float4 v3 = p[3];  // pts[6].x, pts[6].y, pts[7].x, pts[7].y

    float pts[16];
    pts[0]=v0.x; pts[1]=v0.y; pts[2]=v0.z; pts[3]=v0.w;
    pts[4]=v1.x; pts[5]=v1.y; pts[6]=v1.z; pts[7]=v1.w;
    pts[8]=v2.x; pts[9]=v2.y; pts[10]=v2.z; pts[11]=v2.w;
    pts[12]=v3.x; pts[13]=v3.y; pts[14]=v3.z; pts[15]=v3.w;

    float p1x = pts[0];
    float p1y = pts[1];

    int nt = num_of_inter[i] - 2;   // triangles to sum: j < nt, nt in [-2, 6]

    float acc = 0.0f;
    #pragma unroll
    for (int j = 0; j < MAX_TRI; ++j) {
        float p2x = pts[2 * (1 + j)];
        float p2y = pts[2 * (1 + j) + 1];
        float p3x = pts[2 * (2 + j)];
        float p3y = pts[2 * (2 + j) + 1];
        float cross = (p1x - p3x) * (p2y - p3y) - (p1y - p3y) * (p2x - p3x);
        float area = fabsf(cross) * 0.5f;
        acc += (j < nt) ? area : 0.0f;
    }
    out[i] = acc;
}

extern "C" void kernel_launch(void* const* d_in, const int* in_sizes, int n_in,
                              void* d_out, int out_size, void* d_ws, size_t ws_size,
                              hipStream_t stream) {
    const float* int_pts      = (const float*)d_in[0];
    const int*   num_of_inter = (const int*)d_in[1];
    float*       out          = (float*)d_out;
    int n = in_sizes[1];  // N rows (num_of_inter has one element per row)

    const int block = 256;
    const int grid = (n + block - 1) / block;
    rinter_area_kernel<<<grid, block, 0, stream>>>(int_pts, num_of_inter, out, n);
}